// Round 9
// baseline (339.710 us; speedup 1.0000x reference)
//
#include <hip/hip_runtime.h>

typedef float v2f __attribute__((ext_vector_type(2)));

#define BB 32
#define LL 32768
#define HH 32
#define NN2 8
#define NCOND 4
#define NCHUNK 256
#define LC (LL / NCHUNK)   // 128

// ws layout (floats):
//  PARAM_OFF: per h: [wr x8][wi x8][ctr x8][cti x8]   H*32  = 1024
//  WLC_OFF  : per (h,n): (wLc_r, wLc_i)               H*N2*2 = 512   (at 1024)
//  FILM_OFF : per (b,h): (gamma, beta)                B*H*2  = 2048  (at 1536)
//  S_OFF    : per (b,c,h): [zr x8][zi x8]             B*H*NCHUNK*16  (at 4096)
#define PARAM_OFF 0
#define WLC_OFF   1024
#define FILM_OFF  1536
#define S_OFF     4096

static __device__ __forceinline__ v2f vfma(v2f a, v2f b, v2f c) {
  return __builtin_elementwise_fma(a, b, c);
}

// Forced packed fp32 (VOP3P).
static __device__ __forceinline__ v2f pk_fma(v2f a, v2f b, v2f c) {
  v2f d;
  asm("v_pk_fma_f32 %0, %1, %2, %3" : "=v"(d) : "v"(a), "v"(b), "v"(c));
  return d;
}
static __device__ __forceinline__ v2f pk_mul(v2f a, v2f b) {
  v2f d;
  asm("v_pk_mul_f32 %0, %1, %2" : "=v"(d) : "v"(a), "v"(b));
  return d;
}

__global__ void setup_kernel(const float* __restrict__ log_dt,
                             const float* __restrict__ C_re,
                             const float* __restrict__ C_im,
                             const float* __restrict__ log_A_real,
                             const float* __restrict__ A_imag,
                             const float* __restrict__ cond,
                             const float* __restrict__ film_W,
                             const float* __restrict__ film_b,
                             float* __restrict__ ws) {
  int idx = blockIdx.x * blockDim.x + threadIdx.x;
  if (idx < HH * NN2) {
    int h = idx >> 3, n = idx & (NN2 - 1);
    float dt = expf(log_dt[h]);
    float ar = -expf(log_A_real[idx]);
    float ai = A_imag[idx];
    float dr = ar * dt, di = ai * dt;        // dtA
    float er = expf(dr);
    float wr = er * cosf(di);
    float wi = er * sinf(di);
    // (exp(dtA)-1)/A
    float den = ar * ar + ai * ai;
    float tr = ((wr - 1.f) * ar + wi * ai) / den;
    float ti = (wi * ar - (wr - 1.f) * ai) / den;
    float cr = C_re[idx], ci = C_im[idx];
    float ctr = 2.f * (cr * tr - ci * ti);
    float cti = 2.f * (cr * ti + ci * tr);
    float* p = ws + PARAM_OFF + h * 32;
    p[n] = wr; p[n + 8] = wi; p[n + 16] = ctr; p[n + 24] = cti;
    // w^LC
    float eL  = expf(dr * (float)LC);
    float wlr = eL * cosf(di * (float)LC);
    float wli = eL * sinf(di * (float)LC);
    float* q = ws + WLC_OFF + idx * 2;
    q[0] = wlr; q[1] = wli;
  }
  int f = idx - HH * NN2;
  if (f >= 0 && f < BB * HH) {
    int b = f >> 5, h = f & (HH - 1);
    float g  = film_b[h];
    float be = film_b[h + HH];
    #pragma unroll
    for (int c2 = 0; c2 < NCOND; c2++) {
      float cv = cond[b * NCOND + c2];
      g  = fmaf(cv, film_W[c2 * 2 * HH + h], g);
      be = fmaf(cv, film_W[c2 * 2 * HH + HH + h], be);
    }
    float* p = ws + FILM_OFF + f * 2;
    p[0] = g; p[1] = be;
  }
}

// Width experiment: each thread owns an h-PAIR (h0 = 2*h2, h0+1) x 4 modes
// (nh-split). x loads are dwordx2 (8 B/lane, 2x distinct bytes per wave-
// instruction vs dword); stores likewise. Thread decode:
//   flat: h2(4b) | nh(1b) | c(8b) | b(5b)   -> 262144 threads, 1024 blocks.
__global__ __launch_bounds__(256) void pass_a(const float* __restrict__ x,
                                              float* __restrict__ ws) {
  const int flat = blockIdx.x * 256 + threadIdx.x;
  const int h2 = flat & 15;
  const int nh = (flat >> 4) & 1;
  const int c  = (flat >> 5) & (NCHUNK - 1);
  const int b  = flat >> 13;
  const int h0 = h2 << 1;

  v2f wr[2][2], wi[2][2], nwi[2][2], zr[2][2], zi[2][2];
  #pragma unroll
  for (int hh = 0; hh < 2; hh++) {
    const v2f* pp = (const v2f*)(ws + PARAM_OFF + (h0 + hh) * 32);
    #pragma unroll
    for (int g = 0; g < 2; g++) {
      wr[hh][g] = pp[nh * 2 + g]; wi[hh][g] = pp[4 + nh * 2 + g];
      nwi[hh][g] = (v2f){-wi[hh][g].x, -wi[hh][g].y};
      zr[hh][g] = (v2f){0.f, 0.f}; zi[hh][g] = (v2f){0.f, 0.f};
    }
  }
  const float* xp = x + ((size_t)b * LL + (size_t)c * LC) * HH + h0;
  v2f u[4], un[4];
  #pragma unroll
  for (int j = 0; j < 4; j++) u[j] = *(const v2f*)(xp + (size_t)j * HH);
  for (int i = 0; i < LC; i += 4) {
    const int ip = (i + 4 < LC) ? (i + 4) : i;   // uniform, branchless
    #pragma unroll
    for (int j = 0; j < 4; j++) un[j] = *(const v2f*)(xp + (size_t)(ip + j) * HH);
    #pragma unroll
    for (int j = 0; j < 4; j++) {
      v2f us0 = (v2f){u[j].x, u[j].x};
      v2f us1 = (v2f){u[j].y, u[j].y};
      #pragma unroll
      for (int g = 0; g < 2; g++) {
        v2f t0  = pk_fma(nwi[0][g], zi[0][g], us0);
        v2f nzr = pk_fma(wr[0][g], zr[0][g], t0);
        v2f t1  = pk_mul(wi[0][g], zr[0][g]);
        zi[0][g] = pk_fma(wr[0][g], zi[0][g], t1);
        zr[0][g] = nzr;
        v2f s0  = pk_fma(nwi[1][g], zi[1][g], us1);
        v2f mzr = pk_fma(wr[1][g], zr[1][g], s0);
        v2f s1  = pk_mul(wi[1][g], zr[1][g]);
        zi[1][g] = pk_fma(wr[1][g], zi[1][g], s1);
        zr[1][g] = mzr;
      }
    }
    #pragma unroll
    for (int j = 0; j < 4; j++) u[j] = un[j];
  }
  #pragma unroll
  for (int hh = 0; hh < 2; hh++) {
    const size_t flatbch = ((size_t)b * NCHUNK + c) * HH + h0 + hh;
    v2f* Sp = (v2f*)(ws + S_OFF + flatbch * 16);
    #pragma unroll
    for (int g = 0; g < 2; g++) {
      Sp[nh * 2 + g]     = zr[hh][g];
      Sp[4 + nh * 2 + g] = zi[hh][g];
    }
  }
}

// Block-parallel chunk-prefix scan (Hillis-Steele, 8 steps). Unchanged.
__global__ __launch_bounds__(256) void pass_b(float* __restrict__ ws) {
  const int bh = blockIdx.x;            // 0 .. B*H-1
  const int b  = bh >> 5;
  const int h  = bh & (HH - 1);
  const int t  = threadIdx.x;           // chunk index

  __shared__ __align__(16) float Lbuf[NCHUNK][18];   // 16 payload + 2 pad

  float* Sp = ws + S_OFF +
              ((size_t)b * (NCHUNK * HH) + (size_t)t * HH + h) * 16;

  v2f zr[4], zi[4];
  #pragma unroll
  for (int g = 0; g < 4; g++) {
    zr[g] = ((const v2f*)Sp)[g];
    zi[g] = ((const v2f*)Sp)[4 + g];
  }

  const float* q = ws + WLC_OFF + h * NN2 * 2;
  v2f mr[4], mi[4];
  #pragma unroll
  for (int g = 0; g < 4; g++) {
    mr[g] = (v2f){q[4 * g + 0], q[4 * g + 2]};
    mi[g] = (v2f){q[4 * g + 1], q[4 * g + 3]};
  }

  v2f* rowv = (v2f*)&Lbuf[t][0];
  #pragma unroll
  for (int g = 0; g < 4; g++) { rowv[g] = zr[g]; rowv[4 + g] = zi[g]; }
  __syncthreads();

  #pragma unroll
  for (int d = 1; d < NCHUNK; d <<= 1) {
    v2f ar[4], ai[4];
    #pragma unroll
    for (int g = 0; g < 4; g++) { ar[g] = (v2f){0.f, 0.f}; ai[g] = (v2f){0.f, 0.f}; }
    if (t >= d) {
      const v2f* prow = (const v2f*)&Lbuf[t - d][0];
      #pragma unroll
      for (int g = 0; g < 4; g++) { ar[g] = prow[g]; ai[g] = prow[4 + g]; }
    }
    __syncthreads();
    #pragma unroll
    for (int g = 0; g < 4; g++) {
      zr[g] = vfma(mr[g], ar[g], vfma(-mi[g], ai[g], zr[g]));
      zi[g] = vfma(mr[g], ai[g], vfma(mi[g], ar[g], zi[g]));
      rowv[g] = zr[g]; rowv[4 + g] = zi[g];
      v2f nmr = vfma(mr[g], mr[g], -(mi[g] * mi[g]));
      v2f nmi = (mr[g] + mr[g]) * mi[g];
      mr[g] = nmr; mi[g] = nmi;
    }
    __syncthreads();
  }

  v2f er[4], ei[4];
  #pragma unroll
  for (int g = 0; g < 4; g++) { er[g] = (v2f){0.f, 0.f}; ei[g] = (v2f){0.f, 0.f}; }
  if (t > 0) {
    const v2f* prow = (const v2f*)&Lbuf[t - 1][0];
    #pragma unroll
    for (int g = 0; g < 4; g++) { er[g] = prow[g]; ei[g] = prow[4 + g]; }
  }
  #pragma unroll
  for (int g = 0; g < 4; g++) {
    ((v2f*)Sp)[g] = er[g];
    ((v2f*)Sp)[4 + g] = ei[g];
  }
}

// pass_c: h-pair per thread, dwordx2 loads/stores, pk-asm recurrence,
// cheap sigmoid-gelu. nh lanes are xor-16 partners.
__global__ __launch_bounds__(256) void pass_c(const float* __restrict__ x,
                                              const float* __restrict__ Dv,
                                              float* __restrict__ out,
                                              float* __restrict__ ws) {
  const int flat = blockIdx.x * 256 + threadIdx.x;
  const int h2 = flat & 15;
  const int nh = (flat >> 4) & 1;
  const int c  = (flat >> 5) & (NCHUNK - 1);
  const int b  = flat >> 13;
  const int h0 = h2 << 1;

  v2f wr[2][2], wi[2][2], nwi[2][2], ctr[2][2], ncti[2][2], zr[2][2], zi[2][2];
  #pragma unroll
  for (int hh = 0; hh < 2; hh++) {
    const v2f* pp = (const v2f*)(ws + PARAM_OFF + (h0 + hh) * 32);
    #pragma unroll
    for (int g = 0; g < 2; g++) {
      wr[hh][g]  = pp[nh * 2 + g];      wi[hh][g]  = pp[4 + nh * 2 + g];
      nwi[hh][g] = (v2f){-wi[hh][g].x, -wi[hh][g].y};
      ctr[hh][g] = pp[8 + nh * 2 + g];
      v2f ct = pp[12 + nh * 2 + g];
      ncti[hh][g] = (v2f){-ct.x, -ct.y};
    }
    const size_t flatbch = ((size_t)b * NCHUNK + c) * HH + h0 + hh;
    const v2f* Zp = (const v2f*)(ws + S_OFF + flatbch * 16);
    #pragma unroll
    for (int g = 0; g < 2; g++) {
      zr[hh][g] = Zp[nh * 2 + g];
      zi[hh][g] = Zp[4 + nh * 2 + g];
    }
  }
  v2f gam, bet, dco;
  {
    const float* fp = ws + FILM_OFF + ((size_t)b * HH + h0) * 2;
    gam = (v2f){fp[0], fp[2]};
    bet = (v2f){fp[1], fp[3]};
    dco = (v2f){Dv[h0], Dv[h0 + 1]};
  }
  const size_t off = ((size_t)b * LL + (size_t)c * LC) * HH + h0;
  const float* xp = x + off;
  float* op = out + off;
  v2f u[4], un[4];
  #pragma unroll
  for (int j = 0; j < 4; j++) u[j] = *(const v2f*)(xp + (size_t)j * HH);
  for (int i = 0; i < LC; i += 4) {
    const int ip = (i + 4 < LC) ? (i + 4) : i;   // uniform, branchless
    #pragma unroll
    for (int j = 0; j < 4; j++) un[j] = *(const v2f*)(xp + (size_t)(ip + j) * HH);
    #pragma unroll
    for (int j = 0; j < 4; j += 2) {
      v2f yv[2];
      #pragma unroll
      for (int e = 0; e < 2; e++) {      // elements j, j+1
        v2f uu = u[j + e];
        v2f us0 = (v2f){uu.x, uu.x};
        v2f us1 = (v2f){uu.y, uu.y};
        v2f a0 = (v2f){0.f, 0.f}, a1 = (v2f){0.f, 0.f};
        #pragma unroll
        for (int g = 0; g < 2; g++) {
          v2f t0  = pk_fma(nwi[0][g], zi[0][g], us0);
          v2f nzr = pk_fma(wr[0][g], zr[0][g], t0);
          v2f t1  = pk_mul(wi[0][g], zr[0][g]);
          zi[0][g] = pk_fma(wr[0][g], zi[0][g], t1);
          zr[0][g] = nzr;
          a0 = pk_fma(ctr[0][g], zr[0][g], a0);
          a0 = pk_fma(ncti[0][g], zi[0][g], a0);
          v2f s0  = pk_fma(nwi[1][g], zi[1][g], us1);
          v2f mzr = pk_fma(wr[1][g], zr[1][g], s0);
          v2f s1  = pk_mul(wi[1][g], zr[1][g]);
          zi[1][g] = pk_fma(wr[1][g], zi[1][g], s1);
          zr[1][g] = mzr;
          a1 = pk_fma(ctr[1][g], zr[1][g], a1);
          a1 = pk_fma(ncti[1][g], zi[1][g], a1);
        }
        yv[e] = (v2f){a0.x + a0.y, a1.x + a1.y};   // {y_h0, y_h1} partial
      }
      // combine nh-halves (xor-16 partners hold the other 4 modes)
      #pragma unroll
      for (int e = 0; e < 2; e++) {
        yv[e].x += __shfl_xor(yv[e].x, 16, 64);
        yv[e].y += __shfl_xor(yv[e].y, 16, 64);
      }
      // each nh-lane finishes one element: nh=0 -> j, nh=1 -> j+1
      v2f ysel = nh ? yv[1] : yv[0];
      v2f usel = nh ? u[j + 1] : u[j];
      v2f y = vfma(dco, usel, ysel);
      y = vfma(gam, y, bet);
      // gelu(tanh approx) == y * sigmoid(1.5957691*y + 0.0713548755*y^3)
      v2f y2 = y * y;
      v2f s  = y * vfma((v2f){0.0713548755f, 0.0713548755f}, y2,
                        (v2f){1.5957691216f, 1.5957691216f});
      float e0 = __expf(-s.x);
      float e1 = __expf(-s.y);
      float r0 = __fdividef(y.x, 1.f + e0);
      float r1 = __fdividef(y.y, 1.f + e1);
      v2f res = (v2f){r0, r1};
      __builtin_nontemporal_store(res, (v2f*)(op + (size_t)(i + j + nh) * HH));
    }
    #pragma unroll
    for (int j = 0; j < 4; j++) u[j] = un[j];
  }
}

extern "C" void kernel_launch(void* const* d_in, const int* in_sizes, int n_in,
                              void* d_out, int out_size, void* d_ws, size_t ws_size,
                              hipStream_t stream) {
  const float* x          = (const float*)d_in[0];
  const float* cond       = (const float*)d_in[1];
  const float* log_dt     = (const float*)d_in[2];
  const float* C_re       = (const float*)d_in[3];
  const float* C_im       = (const float*)d_in[4];
  const float* log_A_real = (const float*)d_in[5];
  const float* A_imag     = (const float*)d_in[6];
  const float* Dv         = (const float*)d_in[7];
  const float* film_W     = (const float*)d_in[8];
  const float* film_b     = (const float*)d_in[9];
  float* out = (float*)d_out;
  float* ws  = (float*)d_ws;

  setup_kernel<<<5, 256, 0, stream>>>(log_dt, C_re, C_im, log_A_real, A_imag,
                                      cond, film_W, film_b, ws);
  pass_a<<<(BB * HH * NCHUNK) / 256, 256, 0, stream>>>(x, ws);
  pass_b<<<BB * HH, 256, 0, stream>>>(ws);
  pass_c<<<(BB * HH * NCHUNK) / 256, 256, 0, stream>>>(x, Dv, out, ws);
}

// Round 10
// 317.682 us; speedup vs baseline: 1.0693x; 1.0693x over previous
//
#include <hip/hip_runtime.h>

typedef float v2f __attribute__((ext_vector_type(2)));

#define BB 32
#define LL 32768
#define HH 32
#define NN2 8
#define NCOND 4
#define NCHUNK 512
#define LC (LL / NCHUNK)   // 64

// ws layout (floats):
//  PARAM_OFF: per h: [wr x8][wi x8][ctr x8][cti x8]   H*32  = 1024
//  WLC_OFF  : per (h,n): (wLc_r, wLc_i)               H*N2*2 = 512   (at 1024)
//  FILM_OFF : per (b,h): (gamma, beta)                B*H*2  = 2048  (at 1536)
//  S_OFF    : per (b,c,h): [zr x8][zi x8]             B*H*NCHUNK*16  (at 4096)
//             = 33.6 MB. pass_a writes chunk end-states; pass_b rewrites
//             IN PLACE with exclusive prefixes; pass_c reads them.
#define PARAM_OFF 0
#define WLC_OFF   1024
#define FILM_OFF  1536
#define S_OFF     4096

static __device__ __forceinline__ v2f vfma(v2f a, v2f b, v2f c) {
  return __builtin_elementwise_fma(a, b, c);
}

__global__ void setup_kernel(const float* __restrict__ log_dt,
                             const float* __restrict__ C_re,
                             const float* __restrict__ C_im,
                             const float* __restrict__ log_A_real,
                             const float* __restrict__ A_imag,
                             const float* __restrict__ cond,
                             const float* __restrict__ film_W,
                             const float* __restrict__ film_b,
                             float* __restrict__ ws) {
  int idx = blockIdx.x * blockDim.x + threadIdx.x;
  if (idx < HH * NN2) {
    int h = idx >> 3, n = idx & (NN2 - 1);
    float dt = expf(log_dt[h]);
    float ar = -expf(log_A_real[idx]);
    float ai = A_imag[idx];
    float dr = ar * dt, di = ai * dt;        // dtA
    float er = expf(dr);
    float wr = er * cosf(di);
    float wi = er * sinf(di);
    // (exp(dtA)-1)/A
    float den = ar * ar + ai * ai;
    float tr = ((wr - 1.f) * ar + wi * ai) / den;
    float ti = (wi * ar - (wr - 1.f) * ai) / den;
    float cr = C_re[idx], ci = C_im[idx];
    float ctr = 2.f * (cr * tr - ci * ti);
    float cti = 2.f * (cr * ti + ci * tr);
    float* p = ws + PARAM_OFF + h * 32;
    p[n] = wr; p[n + 8] = wi; p[n + 16] = ctr; p[n + 24] = cti;
    // w^LC
    float eL  = expf(dr * (float)LC);
    float wlr = eL * cosf(di * (float)LC);
    float wli = eL * sinf(di * (float)LC);
    float* q = ws + WLC_OFF + idx * 2;
    q[0] = wlr; q[1] = wli;
  }
  int f = idx - HH * NN2;
  if (f >= 0 && f < BB * HH) {
    int b = f >> 5, h = f & (HH - 1);
    float g  = film_b[h];
    float be = film_b[h + HH];
    #pragma unroll
    for (int c2 = 0; c2 < NCOND; c2++) {
      float cv = cond[b * NCOND + c2];
      g  = fmaf(cv, film_W[c2 * 2 * HH + h], g);
      be = fmaf(cv, film_W[c2 * 2 * HH + HH + h], be);
    }
    float* p = ws + FILM_OFF + f * 2;
    p[0] = g; p[1] = be;
  }
}

// Max-TLP, zero-shuffle: ONE thread per (b,c,h) owning all 8 modes.
// NCHUNK=512 (LC=64) doubles the wave pool vs round-8 (8192 waves).
// Scalar x loads (coalesced across h), 8-deep prefetch.
__global__ __launch_bounds__(256) void pass_a(const float* __restrict__ x,
                                              float* __restrict__ ws) {
  const int flat = blockIdx.x * 256 + threadIdx.x;
  const int h = flat & (HH - 1);
  const int c = (flat >> 5) & (NCHUNK - 1);
  const int b = flat >> 14;
  const v2f* pp = (const v2f*)(ws + PARAM_OFF + h * 32);
  v2f wr[4], wi[4], zr[4], zi[4];
  #pragma unroll
  for (int g = 0; g < 4; g++) {
    wr[g] = pp[g]; wi[g] = pp[4 + g];
    zr[g] = (v2f){0.f, 0.f}; zi[g] = (v2f){0.f, 0.f};
  }
  const float* xp = x + ((size_t)b * LL + (size_t)c * LC) * HH + h;
  float u[8], un[8];
  #pragma unroll
  for (int j = 0; j < 8; j++) u[j] = xp[(size_t)j * HH];
  for (int i = 0; i < LC; i += 8) {
    const int ip = (i + 8 < LC) ? (i + 8) : i;   // uniform, branchless
    #pragma unroll
    for (int j = 0; j < 8; j++) un[j] = xp[(size_t)(ip + j) * HH];
    #pragma unroll
    for (int j = 0; j < 8; j++) {
      v2f us = (v2f){u[j], u[j]};
      #pragma unroll
      for (int g = 0; g < 4; g++) {
        v2f t0  = vfma(-wi[g], zi[g], us);
        v2f nzr = vfma(wr[g], zr[g], t0);
        v2f nzi = vfma(wr[g], zi[g], wi[g] * zr[g]);
        zr[g] = nzr; zi[g] = nzi;
      }
    }
    #pragma unroll
    for (int j = 0; j < 8; j++) u[j] = un[j];
  }
  v2f* Sp = (v2f*)(ws + S_OFF + (size_t)flat * 16);
  #pragma unroll
  for (int g = 0; g < 4; g++) { Sp[g] = zr[g]; Sp[4 + g] = zi[g]; }
}

// Block-parallel chunk-prefix scan, 512 chunks, 512-thread blocks (9 steps).
__global__ __launch_bounds__(512) void pass_b(float* __restrict__ ws) {
  const int bh = blockIdx.x;            // 0 .. B*H-1
  const int b  = bh >> 5;
  const int h  = bh & (HH - 1);
  const int t  = threadIdx.x;           // chunk index 0..511

  __shared__ __align__(16) float Lbuf[NCHUNK][18];   // 36 KB

  float* Sp = ws + S_OFF +
              ((size_t)b * (NCHUNK * HH) + (size_t)t * HH + h) * 16;

  v2f zr[4], zi[4];
  #pragma unroll
  for (int g = 0; g < 4; g++) {
    zr[g] = ((const v2f*)Sp)[g];
    zi[g] = ((const v2f*)Sp)[4 + g];
  }

  const float* q = ws + WLC_OFF + h * NN2 * 2;
  v2f mr[4], mi[4];
  #pragma unroll
  for (int g = 0; g < 4; g++) {
    mr[g] = (v2f){q[4 * g + 0], q[4 * g + 2]};
    mi[g] = (v2f){q[4 * g + 1], q[4 * g + 3]};
  }

  v2f* rowv = (v2f*)&Lbuf[t][0];
  #pragma unroll
  for (int g = 0; g < 4; g++) { rowv[g] = zr[g]; rowv[4 + g] = zi[g]; }
  __syncthreads();

  #pragma unroll
  for (int d = 1; d < NCHUNK; d <<= 1) {
    v2f ar[4], ai[4];
    #pragma unroll
    for (int g = 0; g < 4; g++) { ar[g] = (v2f){0.f, 0.f}; ai[g] = (v2f){0.f, 0.f}; }
    if (t >= d) {
      const v2f* prow = (const v2f*)&Lbuf[t - d][0];
      #pragma unroll
      for (int g = 0; g < 4; g++) { ar[g] = prow[g]; ai[g] = prow[4 + g]; }
    }
    __syncthreads();
    #pragma unroll
    for (int g = 0; g < 4; g++) {
      zr[g] = vfma(mr[g], ar[g], vfma(-mi[g], ai[g], zr[g]));
      zi[g] = vfma(mr[g], ai[g], vfma(mi[g], ar[g], zi[g]));
      rowv[g] = zr[g]; rowv[4 + g] = zi[g];
      v2f nmr = vfma(mr[g], mr[g], -(mi[g] * mi[g]));
      v2f nmi = (mr[g] + mr[g]) * mi[g];
      mr[g] = nmr; mi[g] = nmi;
    }
    __syncthreads();
  }

  v2f er[4], ei[4];
  #pragma unroll
  for (int g = 0; g < 4; g++) { er[g] = (v2f){0.f, 0.f}; ei[g] = (v2f){0.f, 0.f}; }
  if (t > 0) {
    const v2f* prow = (const v2f*)&Lbuf[t - 1][0];
    #pragma unroll
    for (int g = 0; g < 4; g++) { er[g] = prow[g]; ei[g] = prow[4 + g]; }
  }
  #pragma unroll
  for (int g = 0; g < 4; g++) {
    ((v2f*)Sp)[g] = er[g];
    ((v2f*)Sp)[4 + g] = ei[g];
  }
}

// pass_c: one thread per (b,c,h), all 8 modes, zero shuffles, scalar loads
// with prefetch, builtin packed fma, cheap sigmoid-gelu, nontemporal store.
__global__ __launch_bounds__(256) void pass_c(const float* __restrict__ x,
                                              const float* __restrict__ Dv,
                                              float* __restrict__ out,
                                              float* __restrict__ ws) {
  const int flat = blockIdx.x * 256 + threadIdx.x;
  const int h = flat & (HH - 1);
  const int c = (flat >> 5) & (NCHUNK - 1);
  const int b = flat >> 14;
  const v2f* pp = (const v2f*)(ws + PARAM_OFF + h * 32);
  v2f wr[4], wi[4], ctr[4], cti[4], zr[4], zi[4];
  #pragma unroll
  for (int g = 0; g < 4; g++) {
    wr[g] = pp[g]; wi[g] = pp[4 + g]; ctr[g] = pp[8 + g]; cti[g] = pp[12 + g];
  }
  const v2f* Zp = (const v2f*)(ws + S_OFF + (size_t)flat * 16);
  #pragma unroll
  for (int g = 0; g < 4; g++) { zr[g] = Zp[g]; zi[g] = Zp[4 + g]; }
  float gamma = ws[FILM_OFF + ((size_t)b * HH + h) * 2];
  float beta  = ws[FILM_OFF + ((size_t)b * HH + h) * 2 + 1];
  float dcoef = Dv[h];
  const size_t off = ((size_t)b * LL + (size_t)c * LC) * HH + h;
  const float* xp = x + off;
  float* op = out + off;
  float u[8], un[8];
  #pragma unroll
  for (int j = 0; j < 8; j++) u[j] = xp[(size_t)j * HH];
  for (int i = 0; i < LC; i += 8) {
    const int ip = (i + 8 < LC) ? (i + 8) : i;   // uniform, branchless
    #pragma unroll
    for (int j = 0; j < 8; j++) un[j] = xp[(size_t)(ip + j) * HH];
    #pragma unroll
    for (int j = 0; j < 8; j++) {
      v2f us = (v2f){u[j], u[j]};
      v2f acc = (v2f){0.f, 0.f};
      #pragma unroll
      for (int g = 0; g < 4; g++) {
        v2f t0  = vfma(-wi[g], zi[g], us);
        v2f nzr = vfma(wr[g], zr[g], t0);
        v2f nzi = vfma(wr[g], zi[g], wi[g] * zr[g]);
        zr[g] = nzr; zi[g] = nzi;
        acc = vfma(ctr[g], nzr, acc);
        acc = vfma(-cti[g], nzi, acc);
      }
      float y = acc.x + acc.y;
      y = fmaf(dcoef, u[j], y);
      y = fmaf(gamma, y, beta);
      // gelu(tanh approx) == y * sigmoid(1.5957691*y + 0.0713548755*y^3)
      float y2 = y * y;
      float s  = y * fmaf(0.0713548755f, y2, 1.5957691216f);
      float ex = __expf(-s);
      float r  = __fdividef(y, 1.f + ex);
      __builtin_nontemporal_store(r, op + (size_t)(i + j) * HH);
    }
    #pragma unroll
    for (int j = 0; j < 8; j++) u[j] = un[j];
  }
}

extern "C" void kernel_launch(void* const* d_in, const int* in_sizes, int n_in,
                              void* d_out, int out_size, void* d_ws, size_t ws_size,
                              hipStream_t stream) {
  const float* x          = (const float*)d_in[0];
  const float* cond       = (const float*)d_in[1];
  const float* log_dt     = (const float*)d_in[2];
  const float* C_re       = (const float*)d_in[3];
  const float* C_im       = (const float*)d_in[4];
  const float* log_A_real = (const float*)d_in[5];
  const float* A_imag     = (const float*)d_in[6];
  const float* Dv         = (const float*)d_in[7];
  const float* film_W     = (const float*)d_in[8];
  const float* film_b     = (const float*)d_in[9];
  float* out = (float*)d_out;
  float* ws  = (float*)d_ws;

  setup_kernel<<<5, 256, 0, stream>>>(log_dt, C_re, C_im, log_A_real, A_imag,
                                      cond, film_W, film_b, ws);
  pass_a<<<(BB * HH * NCHUNK) / 256, 256, 0, stream>>>(x, ws);
  pass_b<<<BB * HH, 512, 0, stream>>>(ws);
  pass_c<<<(BB * HH * NCHUNK) / 256, 256, 0, stream>>>(x, Dv, out, ws);
}